// Round 5
// baseline (3364.029 us; speedup 1.0000x reference)
//
#include <hip/hip_runtime.h>
#include <hip/hip_bf16.h>

// GraphCastEdgeBlock fused persistent kernel for MI355X (gfx950).
// h = silu(LN(concat(ea, ns[src], nd[dst]) @ W1 + b1)); out = ea + h @ W2 + b2
// E=600000, N=50000, D=128, H=512, in=384. fp32 I/O; bf16 MFMA compute.
// Persistent 512 blocks, MTILE=32, LDS-double-buffered x, staging pipelined
// one tile ahead (issue during GEMM2-p1, consume after epilogue).

#define E_TOTAL 600000
#define DD      128
#define HH      512
#define IND     384
#define MT      32
#define XS      392   // x row stride (bf16); 784B -> 4-bank row shift, ~2-way
#define AS      264   // act-half row stride (bf16); 528B -> 4-bank row shift
#define NT      18750 // E_TOTAL / MT
#define NBLK    512   // persistent blocks (2 per CU)

typedef __attribute__((ext_vector_type(8))) short bf16x8;
typedef __attribute__((ext_vector_type(4))) float f32x4;

__device__ __forceinline__ ushort f2bf(float f) {
    __hip_bfloat16 b = __float2bfloat16(f);
    return *reinterpret_cast<ushort*>(&b);
}
__device__ __forceinline__ ushort4 cvt4(float4 v) {
    ushort4 u = { f2bf(v.x), f2bf(v.y), f2bf(v.z), f2bf(v.w) };
    return u;
}

template <int CTRL>
__device__ __forceinline__ float dpp_add(float x) {
    union { float f; int i; } a, b;
    a.f = x;
    b.i = __builtin_amdgcn_update_dpp(0, a.i, CTRL, 0xf, 0xf, true);
    return x + b.f;
}
// sum across each 16-lane row (all lanes get the sum); pure VALU
__device__ __forceinline__ float row16_sum(float s) {
    s = dpp_add<0xB1>(s);    // quad_perm xor1
    s = dpp_add<0x4E>(s);    // quad_perm xor2
    s = dpp_add<0x124>(s);   // row_ror:4
    s = dpp_add<0x128>(s);   // row_ror:8
    return s;
}

// W1 [384][512] f32 -> W1t [512][384] bf16 ; W2 [512][128] f32 -> W2t [128][512] bf16
__global__ void prep_weights(const float* __restrict__ W1, const float* __restrict__ W2,
                             ushort* __restrict__ W1t, ushort* __restrict__ W2t) {
    int j = blockIdx.x * 256 + threadIdx.x;
    if (j < IND * HH) {
        int n = j / IND, k = j % IND;
        W1t[j] = f2bf(W1[k * HH + n]);
    }
    int j2 = j - IND * HH;
    if (j2 >= 0 && j2 < HH * DD) {
        int d2 = j2 / HH, k = j2 % HH;
        W2t[j2] = f2bf(W2[k * DD + d2]);
    }
}

__global__ __launch_bounds__(512, 4) void edge_persistent_kernel(
    const float* __restrict__ edge_attr,
    const float* __restrict__ nsrc,
    const float* __restrict__ ndst,
    const int*   __restrict__ eidx,
    const float* __restrict__ b1,
    const float* __restrict__ g1,
    const float* __restrict__ be1,
    const float* __restrict__ b2,
    const ushort* __restrict__ W1t,
    const ushort* __restrict__ W2t,
    float* __restrict__ out)
{
    __shared__ __align__(16) ushort xb[2 * MT * XS];   // 50176 B
    __shared__ float red_s[MT][8];
    __shared__ float red_q[MT][8];
    __shared__ __align__(8) float stats[MT][2];

    const int tid  = threadIdx.x;
    const int lane = tid & 63;
    const int w    = tid >> 6;          // wave 0..7
    const int g    = lane >> 4;         // quarter-wave 0..3
    const int li   = lane & 15;
    const int wn0  = w * 64;            // GEMM1 column base

    // hoisted per-wave constants (persistent across tiles)
    float b1v[4], g1v[4], bev[4];
    #pragma unroll
    for (int ni = 0; ni < 4; ++ni) {
        int c = wn0 + ni * 16 + li;
        b1v[ni] = b1[c]; g1v[ni] = g1[c]; bev[ni] = be1[c];
    }
    const float b2v = b2[w * 16 + li];
    const ushort* w1p = W1t + (size_t)(wn0 + li) * IND + g * 8;
    const ushort* w2p = W2t + (size_t)(w * 16 + li) * HH + g * 8;

    // staging thread map: waves 0..3 (256 threads): 8 threads/row, 12 float4 each
    const int sr = tid >> 3;            // 0..31 (valid when w<4)
    const int sp = tid & 7;             // 0..7

    const int t0 = blockIdx.x;

    // ---- prologue: stage tile t0 into xb[0] ----
    if (w < 4) {
        const int en = t0 * MT + sr;
        const int sie = eidx[en];
        const int die = eidx[E_TOTAL + en];
        float4 p0[4], p1[4], p2[4];
        #pragma unroll
        for (int j = 0; j < 4; ++j) p0[j] = *(const float4*)&edge_attr[(size_t)en * DD + sp * 4 + j * 32];
        #pragma unroll
        for (int j = 0; j < 4; ++j) p1[j] = *(const float4*)&nsrc[(size_t)sie * DD + sp * 4 + j * 32];
        #pragma unroll
        for (int j = 0; j < 4; ++j) p2[j] = *(const float4*)&ndst[(size_t)die * DD + sp * 4 + j * 32];
        ushort* dr = &xb[sr * XS];
        #pragma unroll
        for (int j = 0; j < 4; ++j) *(ushort4*)&dr[      sp * 4 + j * 32] = cvt4(p0[j]);
        #pragma unroll
        for (int j = 0; j < 4; ++j) *(ushort4*)&dr[128 + sp * 4 + j * 32] = cvt4(p1[j]);
        #pragma unroll
        for (int j = 0; j < 4; ++j) *(ushort4*)&dr[256 + sp * 4 + j * 32] = cvt4(p2[j]);
    }
    __syncthreads();   // barrier A (tile t0 staged)

    int bs = 0;
    for (int t = t0; t < NT; t += NBLK, bs ^= 1) {
        ushort* cur = &xb[bs * MT * XS];
        ushort* oth = &xb[(bs ^ 1) * MT * XS];
        const int e0 = t * MT;
        const int tn = t + NBLK;
        const bool hn = (tn < NT);

        // ---- GEMM1: h[32][512] = x @ W1 ----
        f32x4 acc[2][4];
        #pragma unroll
        for (int mi = 0; mi < 2; ++mi)
            #pragma unroll
            for (int ni = 0; ni < 4; ++ni)
                acc[mi][ni] = (f32x4){0.f, 0.f, 0.f, 0.f};

        bf16x8 B1b[2][4];
        #pragma unroll
        for (int ni = 0; ni < 4; ++ni) B1b[0][ni] = *(const bf16x8*)(w1p + ni * 16 * IND);
        #pragma unroll
        for (int ni = 0; ni < 4; ++ni) B1b[1][ni] = *(const bf16x8*)(w1p + ni * 16 * IND + 32);

        #pragma unroll
        for (int kb = 0; kb < 12; ++kb) {
            const int c2 = kb & 1;
            const int ko = kb * 32 + g * 8;
            bf16x8 a[2];
            #pragma unroll
            for (int mi = 0; mi < 2; ++mi)
                a[mi] = *(const bf16x8*)&cur[(mi * 16 + li) * XS + ko];
            __builtin_amdgcn_s_setprio(1);
            #pragma unroll
            for (int mi = 0; mi < 2; ++mi)
                #pragma unroll
                for (int ni = 0; ni < 4; ++ni)
                    acc[mi][ni] = __builtin_amdgcn_mfma_f32_16x16x32_bf16(
                        a[mi], B1b[c2][ni], acc[mi][ni], 0, 0, 0);
            __builtin_amdgcn_s_setprio(0);
            if (kb < 10) {
                #pragma unroll
                for (int ni = 0; ni < 4; ++ni)
                    B1b[c2][ni] = *(const bf16x8*)(w1p + ni * 16 * IND + (kb + 2) * 32);
            }
        }

        // ---- bias + row stats ----
        #pragma unroll
        for (int mi = 0; mi < 2; ++mi) {
            #pragma unroll
            for (int reg = 0; reg < 4; ++reg) {
                float s = 0.f, q = 0.f;
                #pragma unroll
                for (int ni = 0; ni < 4; ++ni) {
                    float h = acc[mi][ni][reg] + b1v[ni];
                    acc[mi][ni][reg] = h;
                    s += h;
                    q = fmaf(h, h, q);
                }
                s = row16_sum(s);
                q = row16_sum(q);
                if (li == 0) {
                    int row = mi * 16 + g * 4 + reg;
                    red_s[row][w] = s;
                    red_q[row][w] = q;
                }
            }
        }
        __syncthreads();   // B

        if (tid < MT) {
            float s = 0.f, q = 0.f;
            #pragma unroll
            for (int i = 0; i < 8; ++i) { s += red_s[tid][i]; q += red_q[tid][i]; }
            float mu  = s * (1.f / 512.f);
            float var = q * (1.f / 512.f) - mu * mu;
            stats[tid][0] = mu;
            stats[tid][1] = rsqrtf(var + 1e-5f);
        }
        __syncthreads();   // C

        // ---- LN+SiLU half 1 (waves 0-3, cols < 256) -> act-h1 over dead x ----
        if (w < 4) {
            #pragma unroll
            for (int mi = 0; mi < 2; ++mi) {
                #pragma unroll
                for (int reg = 0; reg < 4; ++reg) {
                    int row = mi * 16 + g * 4 + reg;
                    float2 st = *(float2*)&stats[row][0];
                    #pragma unroll
                    for (int ni = 0; ni < 4; ++ni) {
                        float sc = st.y * g1v[ni];
                        float tc = fmaf(-st.x, sc, bev[ni]);
                        float xn = fmaf(acc[mi][ni][reg], sc, tc);
                        float ex = __expf(-xn);
                        float av = xn * __builtin_amdgcn_rcpf(1.f + ex);
                        cur[row * AS + wn0 + ni * 16 + li] = f2bf(av);
                    }
                }
            }
        }
        // B2 pass-1 frags (all waves; hides under LN writes)
        bf16x8 B2a[8];
        #pragma unroll
        for (int kb = 0; kb < 8; ++kb) B2a[kb] = *(const bf16x8*)(w2p + kb * 32);
        __syncthreads();   // D

        // ---- GEMM2 pass 1 (k 0..255) + stage-issue for tile tn ----
        f32x4 acc2[2];
        acc2[0] = (f32x4){0.f, 0.f, 0.f, 0.f};
        acc2[1] = (f32x4){0.f, 0.f, 0.f, 0.f};

        float4 sA[4], sB[4], sC[4];
        if (hn && w < 4) {
            const int en = tn * MT + sr;
            const int sie = eidx[en];
            const int die = eidx[E_TOTAL + en];
            #pragma unroll
            for (int j = 0; j < 4; ++j) sA[j] = *(const float4*)&edge_attr[(size_t)en * DD + sp * 4 + j * 32];
            #pragma unroll
            for (int j = 0; j < 4; ++j) sB[j] = *(const float4*)&nsrc[(size_t)sie * DD + sp * 4 + j * 32];
            #pragma unroll
            for (int j = 0; j < 4; ++j) sC[j] = *(const float4*)&ndst[(size_t)die * DD + sp * 4 + j * 32];
        }

        #pragma unroll
        for (int kb = 0; kb < 8; ++kb) {
            const int ko = kb * 32 + g * 8;
            bf16x8 a2[2];
            #pragma unroll
            for (int mi = 0; mi < 2; ++mi)
                a2[mi] = *(const bf16x8*)&cur[(mi * 16 + li) * AS + ko];
            __builtin_amdgcn_s_setprio(1);
            #pragma unroll
            for (int mi = 0; mi < 2; ++mi)
                acc2[mi] = __builtin_amdgcn_mfma_f32_16x16x32_bf16(a2[mi], B2a[kb], acc2[mi], 0, 0, 0);
            __builtin_amdgcn_s_setprio(0);
        }
        __syncthreads();   // E (pass-1 reads done)

        // ---- LN+SiLU half 2 (waves 4-7 recompute from live acc) -> act-h2 ----
        if (w >= 4) {
            #pragma unroll
            for (int mi = 0; mi < 2; ++mi) {
                #pragma unroll
                for (int reg = 0; reg < 4; ++reg) {
                    int row = mi * 16 + g * 4 + reg;
                    float2 st = *(float2*)&stats[row][0];
                    #pragma unroll
                    for (int ni = 0; ni < 4; ++ni) {
                        float sc = st.y * g1v[ni];
                        float tc = fmaf(-st.x, sc, bev[ni]);
                        float xn = fmaf(acc[mi][ni][reg], sc, tc);
                        float ex = __expf(-xn);
                        float av = xn * __builtin_amdgcn_rcpf(1.f + ex);
                        cur[row * AS + (wn0 - 256) + ni * 16 + li] = f2bf(av);
                    }
                }
            }
        }
        // B2 pass-2 frags
        bf16x8 B2b[8];
        #pragma unroll
        for (int kb = 0; kb < 8; ++kb) B2b[kb] = *(const bf16x8*)(w2p + (kb + 8) * 32);
        __syncthreads();   // F

        // ---- GEMM2 pass 2 (k 256..511) ----
        #pragma unroll
        for (int kb = 0; kb < 8; ++kb) {
            const int ko = kb * 32 + g * 8;
            bf16x8 a2[2];
            #pragma unroll
            for (int mi = 0; mi < 2; ++mi)
                a2[mi] = *(const bf16x8*)&cur[(mi * 16 + li) * AS + ko];
            __builtin_amdgcn_s_setprio(1);
            #pragma unroll
            for (int mi = 0; mi < 2; ++mi)
                acc2[mi] = __builtin_amdgcn_mfma_f32_16x16x32_bf16(a2[mi], B2b[kb], acc2[mi], 0, 0, 0);
            __builtin_amdgcn_s_setprio(0);
        }

        // ---- epilogue: out = acc2 + b2 + edge_attr (64B-segment direct stores) ----
        #pragma unroll
        for (int mi = 0; mi < 2; ++mi) {
            #pragma unroll
            for (int reg = 0; reg < 4; ++reg) {
                int row = mi * 16 + g * 4 + reg;
                size_t o = (size_t)(e0 + row) * DD + w * 16 + li;
                out[o] = acc2[mi][reg] + b2v + edge_attr[o];
            }
        }

        // ---- consume staged loads -> x(tn) into other buffer ----
        if (hn && w < 4) {
            ushort* dr = &oth[sr * XS];
            #pragma unroll
            for (int j = 0; j < 4; ++j) *(ushort4*)&dr[      sp * 4 + j * 32] = cvt4(sA[j]);
            #pragma unroll
            for (int j = 0; j < 4; ++j) *(ushort4*)&dr[128 + sp * 4 + j * 32] = cvt4(sB[j]);
            #pragma unroll
            for (int j = 0; j < 4; ++j) *(ushort4*)&dr[256 + sp * 4 + j * 32] = cvt4(sC[j]);
        }
        __syncthreads();   // A (next tile staged / buffers swap)
    }
}

extern "C" void kernel_launch(void* const* d_in, const int* in_sizes, int n_in,
                              void* d_out, int out_size, void* d_ws, size_t ws_size,
                              hipStream_t stream) {
    const float* edge_attr = (const float*)d_in[0];
    const float* nsrc      = (const float*)d_in[1];
    const float* ndst      = (const float*)d_in[2];
    const int*   eidx      = (const int*)d_in[3];
    const float* W1        = (const float*)d_in[4];
    const float* b1        = (const float*)d_in[5];
    const float* g1        = (const float*)d_in[6];
    const float* be1       = (const float*)d_in[7];
    const float* W2        = (const float*)d_in[8];
    const float* b2        = (const float*)d_in[9];
    float* out = (float*)d_out;

    ushort* W1t = (ushort*)d_ws;             // 512*384 bf16 = 384 KiB
    ushort* W2t = W1t + IND * HH;            // 128*512 bf16 = 128 KiB

    hipLaunchKernelGGL(prep_weights,
                       dim3((IND * HH + HH * DD + 255) / 256), dim3(256), 0, stream,
                       W1, W2, W1t, W2t);

    hipLaunchKernelGGL(edge_persistent_kernel,
                       dim3(NBLK), dim3(512), 0, stream,
                       edge_attr, nsrc, ndst, eidx, b1, g1, be1, b2, W1t, W2t, out);
}